// Round 8
// baseline (237.796 us; speedup 1.0000x reference)
//
#include <hip/hip_runtime.h>
#include <hip/hip_fp16.h>
#include <math.h>

#define B_ 4
#define N_ 4096
#define D_ 1024
#define H_ 16
#define HD_ 64
#define FB_ 2049

typedef unsigned short ushort_t;
typedef unsigned int uint_t;

__device__ __forceinline__ float2 cmul(float2 a, float2 b) {
    return make_float2(a.x*b.x - a.y*b.y, a.x*b.y + a.y*b.x);
}
__device__ __forceinline__ float2 cadd(float2 a, float2 b){return make_float2(a.x+b.x,a.y+b.y);}
__device__ __forceinline__ float2 csub(float2 a, float2 b){return make_float2(a.x-b.x,a.y-b.y);}
__device__ __forceinline__ float2 cconj(float2 a){return make_float2(a.x,-a.y);}
__device__ __forceinline__ float2 addi(float2 a, float2 b){return make_float2(a.x-b.y, a.y+b.x);}
__device__ __forceinline__ float2 subi(float2 a, float2 b){return make_float2(a.x+b.y, a.y-b.x);}

__device__ __forceinline__ float gelu_t(float m) {
    float u = 0.7978845608028654f * (m + 0.044715f * m * m * m);
    float e = __expf(-2.0f * u);
    float th = (1.0f - e) / (1.0f + e);
    return 0.5f * m * (1.0f + th);
}
__device__ __forceinline__ float2 cact(float2 z) {
    float m = sqrtf(z.x*z.x + z.y*z.y);
    float s = gelu_t(m) / (m + 1e-6f);
    return make_float2(z.x*s, z.y*s);
}

__device__ __forceinline__ ushort_t f2h(float f) {
    __half h = __float2half_rn(f);
    return *reinterpret_cast<ushort_t*>(&h);
}
__device__ __forceinline__ float h2f(ushort_t u) {
    __half h = *reinterpret_cast<__half*>(&u);
    return __half2float(h);
}
__device__ __forceinline__ uint_t pk2(float a, float b) {
    return (uint_t)f2h(a) | ((uint_t)f2h(b) << 16);
}
__device__ __forceinline__ float lo_f(uint_t u){ return h2f((ushort_t)(u & 0xffffu)); }
__device__ __forceinline__ float hi_f(uint_t u){ return h2f((ushort_t)(u >> 16)); }

// skewed LDS index
#define IX(e) ((e) + ((e) >> 4))

// base-8 digit reversal of a 12-bit index
__device__ __forceinline__ int rev12(int p) {
    return ((p & 7) << 9) | (((p >> 3) & 7) << 6) | (((p >> 6) & 7) << 3) | ((p >> 9) & 7);
}

// ---------------- K1: fused LayerNorm stats + apply + transpose (fp16 xt) + cpart --------
// 512 blocks x 512 threads; block = (b, chunk of 32 rows)
__global__ __launch_bounds__(512) void k_normT(const float* __restrict__ x,
                                               const float* __restrict__ lnw,
                                               const float* __restrict__ lnb,
                                               ushort_t* __restrict__ xt,
                                               float* __restrict__ cpart) {
    __shared__ ushort_t lds16[32 * 1032];       // rows stride 516 uints
    uint_t* lds32 = (uint_t*)lds16;
    int blk = blockIdx.x;
    int b = blk >> 7, chunk = blk & 127;
    int n0 = chunk << 5;
    int lane = threadIdx.x & 63, w = threadIdx.x >> 6;   // w = 0..7
    const float4* lw4 = (const float4*)lnw;
    const float4* lb4 = (const float4*)lnb;
    float4 W0 = lw4[lane], W1 = lw4[lane+64], W2 = lw4[lane+128], W3 = lw4[lane+192];
    float4 G0 = lb4[lane], G1 = lb4[lane+64], G2 = lb4[lane+128], G3 = lb4[lane+192];

    for (int j = 0; j < 4; j++) {
        int r = (w << 2) + j;                    // 8 waves x 4 rows = 32 rows
        const float4* xr = (const float4*)(x + ((size_t)b * N_ + n0 + r) * D_);
        float4 v0 = xr[lane], v1 = xr[lane+64], v2 = xr[lane+128], v3 = xr[lane+192];
        float s = v0.x+v0.y+v0.z+v0.w + v1.x+v1.y+v1.z+v1.w
                + v2.x+v2.y+v2.z+v2.w + v3.x+v3.y+v3.z+v3.w;
        float q = v0.x*v0.x+v0.y*v0.y+v0.z*v0.z+v0.w*v0.w
                + v1.x*v1.x+v1.y*v1.y+v1.z*v1.z+v1.w*v1.w
                + v2.x*v2.x+v2.y*v2.y+v2.z*v2.z+v2.w*v2.w
                + v3.x*v3.x+v3.y*v3.y+v3.z*v3.z+v3.w*v3.w;
        for (int o = 1; o < 64; o <<= 1) { s += __shfl_xor(s, o); q += __shfl_xor(q, o); }
        float mu = s * (1.0f / D_);
        float rstd = rsqrtf(q * (1.0f / D_) - mu * mu + 1e-5f);
        int base = r * 516 + 2 * lane;
        lds32[base]       = pk2((v0.x-mu)*rstd*W0.x+G0.x, (v0.y-mu)*rstd*W0.y+G0.y);
        lds32[base + 1]   = pk2((v0.z-mu)*rstd*W0.z+G0.z, (v0.w-mu)*rstd*W0.w+G0.w);
        lds32[base + 128] = pk2((v1.x-mu)*rstd*W1.x+G1.x, (v1.y-mu)*rstd*W1.y+G1.y);
        lds32[base + 129] = pk2((v1.z-mu)*rstd*W1.z+G1.z, (v1.w-mu)*rstd*W1.w+G1.w);
        lds32[base + 256] = pk2((v2.x-mu)*rstd*W2.x+G2.x, (v2.y-mu)*rstd*W2.y+G2.y);
        lds32[base + 257] = pk2((v2.z-mu)*rstd*W2.z+G2.z, (v2.w-mu)*rstd*W2.w+G2.w);
        lds32[base + 384] = pk2((v3.x-mu)*rstd*W3.x+G3.x, (v3.y-mu)*rstd*W3.y+G3.y);
        lds32[base + 385] = pk2((v3.z-mu)*rstd*W3.z+G3.z, (v3.w-mu)*rstd*W3.w+G3.w);
    }
    __syncthreads();
    {
        int dp = threadIdx.x;                    // 0..511
        float cs_e = 0.f, cs_o = 0.f;
        uint_t ce[16], co[16];
        #pragma unroll
        for (int i = 0; i < 16; i++) {
            uint_t w0 = lds32[(2*i) * 516 + dp];
            uint_t w1 = lds32[(2*i+1) * 516 + dp];
            ce[i] = (w0 & 0xffffu) | (w1 << 16);
            co[i] = (w0 >> 16) | (w1 & 0xffff0000u);
            cs_e += lo_f(w0) + lo_f(w1);
            cs_o += hi_f(w0) + hi_f(w1);
        }
        int de = dp * 2;
        uint4* dste = (uint4*)(xt + ((size_t)(b * 1024 + de)) * 4096 + n0);
        dste[0] = make_uint4(ce[0], ce[1], ce[2], ce[3]);
        dste[1] = make_uint4(ce[4], ce[5], ce[6], ce[7]);
        dste[2] = make_uint4(ce[8], ce[9], ce[10], ce[11]);
        dste[3] = make_uint4(ce[12], ce[13], ce[14], ce[15]);
        uint4* dsto = (uint4*)(xt + ((size_t)(b * 1024 + de + 1)) * 4096 + n0);
        dsto[0] = make_uint4(co[0], co[1], co[2], co[3]);
        dsto[1] = make_uint4(co[4], co[5], co[6], co[7]);
        dsto[2] = make_uint4(co[8], co[9], co[10], co[11]);
        dsto[3] = make_uint4(co[12], co[13], co[14], co[15]);
        ((float2*)(cpart + ((size_t)(b * 128 + chunk)) * D_))[dp] = make_float2(cs_e, cs_o);
    }
}

// ---------------- K2: layer-0 partial GEMM, ctx reduction fused ----------------
__global__ __launch_bounds__(256) void k_mlp_part(const float* __restrict__ cpart,
                                                  const float* __restrict__ w,
                                                  float* __restrict__ part) {
    __shared__ float li[4 * 256];
    int ks = blockIdx.y;
    for (int i = threadIdx.x; i < 1024; i += 256) {
        int b = i >> 8, dd = (ks << 8) + (i & 255);
        const float* p = cpart + (size_t)b * 128 * D_ + dd;
        float s = 0.f;
        #pragma unroll 8
        for (int g = 0; g < 128; g++) s += p[g * D_];
        li[i] = s * (1.0f / N_);
    }
    __syncthreads();
    int col = blockIdx.x * 64 + (threadIdx.x & 63);
    int b = threadIdx.x >> 6;
    const float* wp = w + (size_t)(ks * 256) * 1024 + col;
    const float* ip = li + b * 256;
    float acc = 0.f;
    #pragma unroll 8
    for (int k = 0; k < 256; k++) acc = fmaf(ip[k], wp[(size_t)k * 1024], acc);
    part[((size_t)ks * 4 + b) * 1024 + col] = acc;
}

// ---------------- K3: layer-1 partial GEMM ----------------
__global__ __launch_bounds__(256) void k_mlp_part2(const float* __restrict__ part,
                                                   const float* __restrict__ bias,
                                                   const float* __restrict__ w,
                                                   float* __restrict__ part2) {
    __shared__ float li[4 * 256];
    int ks = blockIdx.y;
    for (int i = threadIdx.x; i < 1024; i += 256) {
        int b = i >> 8, kk = (i & 255) + ks * 256;
        float v = part[b * 1024 + kk] + part[4096 + b * 1024 + kk] +
                  part[8192 + b * 1024 + kk] + part[12288 + b * 1024 + kk] + bias[kk];
        li[i] = fmaxf(v, 0.f);
    }
    __syncthreads();
    int col = blockIdx.x * 64 + (threadIdx.x & 63);
    int b = threadIdx.x >> 6;
    const float* wp = w + (size_t)(ks * 256) * 1024 + col;
    const float* ip = li + b * 256;
    float acc = 0.f;
    #pragma unroll 8
    for (int k = 0; k < 256; k++) acc = fmaf(ip[k], wp[(size_t)k * 1024], acc);
    part2[((size_t)ks * 4 + b) * 1024 + col] = acc;
}

// ---------------- K4: w2 partial GEMM ----------------
__global__ __launch_bounds__(256) void k_adapt_part(const float* __restrict__ part2,
                                                    const float* __restrict__ b1,
                                                    const float* __restrict__ w2,
                                                    float* __restrict__ part3) {
    __shared__ float lh[4 * 128];
    int ks = blockIdx.y;
    for (int i = threadIdx.x; i < 512; i += 256) {
        int b = i >> 7, kk = (i & 127) + ks * 128;
        float v = part2[b * 1024 + kk] + part2[4096 + b * 1024 + kk] +
                  part2[8192 + b * 1024 + kk] + part2[12288 + b * 1024 + kk] + b1[kk];
        lh[i] = fmaxf(v, 0.f);
    }
    __syncthreads();
    int j4 = blockIdx.x * 1024 + threadIdx.x * 4;
    if (j4 < 65568) {
        float a0x=0,a0y=0,a0z=0,a0w=0, a1x=0,a1y=0,a1z=0,a1w=0;
        float a2x=0,a2y=0,a2z=0,a2w=0, a3x=0,a3y=0,a3z=0,a3w=0;
        const float* wp = w2 + (size_t)(ks * 128) * 65568 + j4;
        #pragma unroll 4
        for (int k = 0; k < 128; k++) {
            float4 wv = *(const float4*)(wp + (size_t)k * 65568);
            float h0 = lh[k], h1 = lh[128 + k], h2 = lh[256 + k], h3 = lh[384 + k];
            a0x = fmaf(h0, wv.x, a0x); a0y = fmaf(h0, wv.y, a0y);
            a0z = fmaf(h0, wv.z, a0z); a0w = fmaf(h0, wv.w, a0w);
            a1x = fmaf(h1, wv.x, a1x); a1y = fmaf(h1, wv.y, a1y);
            a1z = fmaf(h1, wv.z, a1z); a1w = fmaf(h1, wv.w, a1w);
            a2x = fmaf(h2, wv.x, a2x); a2y = fmaf(h2, wv.y, a2y);
            a2z = fmaf(h2, wv.z, a2z); a2w = fmaf(h2, wv.w, a2w);
            a3x = fmaf(h3, wv.x, a3x); a3y = fmaf(h3, wv.y, a3y);
            a3z = fmaf(h3, wv.z, a3w ? a3w : a3w); a3w = fmaf(h3, wv.w, a3w);
        }
        float* p3 = part3 + (size_t)ks * 4 * 65568 + j4;
        *(float4*)(p3)              = make_float4(a0x, a0y, a0z, a0w);
        *(float4*)(p3 + 65568)      = make_float4(a1x, a1y, a1z, a1w);
        *(float4*)(p3 + 2 * 65568)  = make_float4(a2x, a2y, a2z, a2w);
        *(float4*)(p3 + 3 * 65568)  = make_float4(a3x, a3y, a3z, a3w);
    }
}

// ---------------- K5: finalize adapt -> effective filter/bias ----------------
__global__ __launch_bounds__(256) void k_eff(const float* __restrict__ part3,
                                             const float* __restrict__ b2,
                                             const float* __restrict__ bfilt,
                                             const float* __restrict__ bbias,
                                             float2* __restrict__ eff) {
    int p = blockIdx.x * 256 + threadIdx.x;     // 32784 = H*FB
    if (p >= 32784) return;
    int h = p / 2049, f = p % 2049;
    float bf = bfilt[p], bb = bbias[p];
    float sc = b2[2 * p], bi = b2[2 * p + 1];
    float sc1 = sc, bi1 = bi, sc2 = sc, bi2 = bi, sc3 = sc, bi3 = bi;
    #pragma unroll
    for (int s = 0; s < 8; s++) {
        const float* q0 = part3 + ((size_t)s * 4 + 0) * 65568 + 2 * p;
        const float* q1 = part3 + ((size_t)s * 4 + 1) * 65568 + 2 * p;
        const float* q2 = part3 + ((size_t)s * 4 + 2) * 65568 + 2 * p;
        const float* q3 = part3 + ((size_t)s * 4 + 3) * 65568 + 2 * p;
        sc  += q0[0]; bi  += q0[1];
        sc1 += q1[0]; bi1 += q1[1];
        sc2 += q2[0]; bi2 += q2[1];
        sc3 += q3[0]; bi3 += q3[1];
    }
    eff[((size_t)0 * H_ + h) * FB_ + f] = make_float2(bf * (1.0f + sc),  bb + bi);
    eff[((size_t)1 * H_ + h) * FB_ + f] = make_float2(bf * (1.0f + sc1), bb + bi1);
    eff[((size_t)2 * H_ + h) * FB_ + f] = make_float2(bf * (1.0f + sc2), bb + bi2);
    eff[((size_t)3 * H_ + h) * FB_ + f] = make_float2(bf * (1.0f + sc3), bb + bi3);
}

// ---------------- in-place radix-8 DIF / DIT stages (tree twiddles) ----------------
template<int M, int SH, bool TW>
__device__ __forceinline__ void dif_stage(float2* buf, const float2* tw, int t) {
    const float s2 = 0.70710678118654752f;
    int j = t & (M - 1);
    int base = 8 * t - 7 * j;
    float2 u0 = buf[IX(base)];
    float2 u1 = buf[IX(base + M)];
    float2 u2 = buf[IX(base + 2*M)];
    float2 u3 = buf[IX(base + 3*M)];
    float2 u4 = buf[IX(base + 4*M)];
    float2 u5 = buf[IX(base + 5*M)];
    float2 u6 = buf[IX(base + 6*M)];
    float2 u7 = buf[IX(base + 7*M)];
    float2 a0 = cadd(u0,u4), a1 = csub(u0,u4), a2 = cadd(u2,u6), a3 = csub(u2,u6);
    float2 E0 = cadd(a0,a2), E1 = subi(a1,a3), E2 = csub(a0,a2), E3 = addi(a1,a3);
    float2 c0 = cadd(u1,u5), c1 = csub(u1,u5), c2 = cadd(u3,u7), c3 = csub(u3,u7);
    float2 O0 = cadd(c0,c2), O1 = subi(c1,c3), O2 = csub(c0,c2), O3 = addi(c1,c3);
    float2 R1 = make_float2(s2*(O1.x + O1.y), s2*(O1.y - O1.x));
    float2 R2 = make_float2(O2.y, -O2.x);
    float2 R3 = make_float2(s2*(O3.y - O3.x), -s2*(O3.x + O3.y));
    float2 X0 = cadd(E0,O0), X4 = csub(E0,O0);
    float2 X1 = cadd(E1,R1), X5 = csub(E1,R1);
    float2 X2 = cadd(E2,R2), X6 = csub(E2,R2);
    float2 X3 = cadd(E3,R3), X7 = csub(E3,R3);
    buf[IX(base)] = X0;
    if (TW) {
        float2 w1 = tw[IX(j << SH)];
        float2 w2 = tw[IX(j << (SH + 1))];
        float2 w3 = cmul(w1, w2);
        float2 w4 = cmul(w2, w2);
        float2 w5 = cmul(w2, w3);
        float2 w6 = cmul(w3, w3);
        float2 w7 = cmul(w3, w4);
        buf[IX(base + M)]   = cmul(w1, X1);
        buf[IX(base + 2*M)] = cmul(w2, X2);
        buf[IX(base + 3*M)] = cmul(w3, X3);
        buf[IX(base + 4*M)] = cmul(w4, X4);
        buf[IX(base + 5*M)] = cmul(w5, X5);
        buf[IX(base + 6*M)] = cmul(w6, X6);
        buf[IX(base + 7*M)] = cmul(w7, X7);
    } else {
        buf[IX(base + M)]   = X1;
        buf[IX(base + 2*M)] = X2;
        buf[IX(base + 3*M)] = X3;
        buf[IX(base + 4*M)] = X4;
        buf[IX(base + 5*M)] = X5;
        buf[IX(base + 6*M)] = X6;
        buf[IX(base + 7*M)] = X7;
    }
}

template<int M, int SH, bool TW>
__device__ __forceinline__ void dit_stage(float2* buf, const float2* tw, int t) {
    const float s2 = 0.70710678118654752f;
    int j = t & (M - 1);
    int base = 8 * t - 7 * j;
    float2 u0 = buf[IX(base)];
    float2 u1, u2, u3, u4, u5, u6, u7;
    if (TW) {
        float2 w1 = cconj(tw[IX(j << SH)]);
        float2 w2 = cconj(tw[IX(j << (SH + 1))]);
        float2 w3 = cmul(w1, w2);
        float2 w4 = cmul(w2, w2);
        float2 w5 = cmul(w2, w3);
        float2 w6 = cmul(w3, w3);
        float2 w7 = cmul(w3, w4);
        u1 = cmul(w1, buf[IX(base + M)]);
        u2 = cmul(w2, buf[IX(base + 2*M)]);
        u3 = cmul(w3, buf[IX(base + 3*M)]);
        u4 = cmul(w4, buf[IX(base + 4*M)]);
        u5 = cmul(w5, buf[IX(base + 5*M)]);
        u6 = cmul(w6, buf[IX(base + 6*M)]);
        u7 = cmul(w7, buf[IX(base + 7*M)]);
    } else {
        u1 = buf[IX(base + M)];
        u2 = buf[IX(base + 2*M)];
        u3 = buf[IX(base + 3*M)];
        u4 = buf[IX(base + 4*M)];
        u5 = buf[IX(base + 5*M)];
        u6 = buf[IX(base + 6*M)];
        u7 = buf[IX(base + 7*M)];
    }
    float2 a0 = cadd(u0,u4), a1 = csub(u0,u4), a2 = cadd(u2,u6), a3 = csub(u2,u6);
    float2 E0 = cadd(a0,a2), E1 = addi(a1,a3), E2 = csub(a0,a2), E3 = subi(a1,a3);
    float2 c0 = cadd(u1,u5), c1 = csub(u1,u5), c2 = cadd(u3,u7), c3 = csub(u3,u7);
    float2 O0 = cadd(c0,c2), O1 = addi(c1,c3), O2 = csub(c0,c2), O3 = subi(c1,c3);
    float2 R1 = make_float2(s2*(O1.x - O1.y),  s2*(O1.x + O1.y));
    float2 R2 = make_float2(-O2.y, O2.x);
    float2 R3 = make_float2(-s2*(O3.x + O3.y), s2*(O3.x - O3.y));
    buf[IX(base)]       = cadd(E0,O0);
    buf[IX(base + 4*M)] = csub(E0,O0);
    buf[IX(base + M)]   = cadd(E1,R1);
    buf[IX(base + 5*M)] = csub(E1,R1);
    buf[IX(base + 2*M)] = cadd(E2,R2);
    buf[IX(base + 6*M)] = csub(E2,R2);
    buf[IX(base + 3*M)] = cadd(E3,R3);
    buf[IX(base + 7*M)] = csub(E3,R3);
}

// ---------------- K6: in-place FFT + mod + iFFT, fp16 xt ----------------
__global__ __launch_bounds__(512, 4) void k_fftmod(ushort_t* __restrict__ xt,
                                                   const float2* __restrict__ eff) {
    __shared__ float2 buf[4352];                // 4096 skewed
    __shared__ float2 tw[1088];                 // W_4096^e, e<1024, skewed
    int t = threadIdx.x;
    int sig0 = blockIdx.x * 2;                  // 2048 blocks
    int b = sig0 >> 10;
    int h = (sig0 & 1023) >> 6;
    const float2* ef = eff + ((size_t)b * H_ + h) * FB_;
    ushort_t* xs = xt + (size_t)sig0 * 4096;

    #pragma unroll
    for (int ii = 0; ii < 2; ii++) {
        int e = t + (ii << 9);
        float sv, cv;
        __sincosf(-(float)M_PI * (float)e * (1.0f / 2048.0f), &sv, &cv);
        tw[IX(e)] = make_float2(cv, sv);
    }
    {
        const uint4* pa = (const uint4*)xs;
        const uint4* pb = pa + 512;
        uint4 ua = pa[t], ub = pb[t];
        int n = t << 3;
        buf[IX(n+0)] = make_float2(lo_f(ua.x), lo_f(ub.x));
        buf[IX(n+1)] = make_float2(hi_f(ua.x), hi_f(ub.x));
        buf[IX(n+2)] = make_float2(lo_f(ua.y), lo_f(ub.y));
        buf[IX(n+3)] = make_float2(hi_f(ua.y), hi_f(ub.y));
        buf[IX(n+4)] = make_float2(lo_f(ua.z), lo_f(ub.z));
        buf[IX(n+5)] = make_float2(hi_f(ua.z), hi_f(ub.z));
        buf[IX(n+6)] = make_float2(lo_f(ua.w), lo_f(ub.w));
        buf[IX(n+7)] = make_float2(hi_f(ua.w), hi_f(ub.w));
    }
    __syncthreads();

    dif_stage<512, 0, true >(buf, tw, t); __syncthreads();
    dif_stage<64,  3, true >(buf, tw, t); __syncthreads();
    dif_stage<8,   6, true >(buf, tw, t); __syncthreads();
    dif_stage<1,   0, false>(buf, tw, t); __syncthreads();

    if (t == 0) {                                // k = 0 at p = 0
        float2 Z = buf[IX(0)];
        float2 e0 = ef[0];
        float Av = Z.x * e0.x + e0.y;
        float Bv = Z.y * e0.x + e0.y;
        float ma = fabsf(Av); Av *= gelu_t(ma) / (ma + 1e-6f);
        float mb = fabsf(Bv); Bv *= gelu_t(mb) / (mb + 1e-6f);
        buf[IX(0)] = make_float2(Av, Bv);
    }
    #pragma unroll
    for (int ii = 0; ii < 4; ii++) {
        int k = 1 + t + (ii << 9);               // 1..2048
        if (k == 2048) {                         // Nyquist at p = rev(2048) = 4
            float2 Z = buf[IX(4)];
            float2 eN = ef[2048];
            float Av = Z.x * eN.x + eN.y;
            float Bv = Z.y * eN.x + eN.y;
            float ma = fabsf(Av); Av *= gelu_t(ma) / (ma + 1e-6f);
            float mb = fabsf(Bv); Bv *= gelu_t(mb) / (mb + 1e-6f);
            buf[IX(4)] = make_float2(Av, Bv);
        } else {
            int pk = rev12(k);
            int pq = rev12(4096 - k);
            float2 Zk = buf[IX(pk)], Zq = buf[IX(pq)];
            float2 A  = make_float2(0.5f*(Zk.x + Zq.x), 0.5f*(Zk.y - Zq.y));
            float2 Bc = make_float2(0.5f*(Zk.y + Zq.y), 0.5f*(Zq.x - Zk.x));
            float2 e = ef[k];
            float2 Ap = make_float2(A.x * e.x + e.y,  A.y * e.x);
            float2 Bp = make_float2(Bc.x * e.x + e.y, Bc.y * e.x);
            Ap = cact(Ap); Bp = cact(Bp);
            buf[IX(pk)] = make_float2(Ap.x - Bp.y, Ap.y + Bp.x);
            buf[IX(pq)] = make_float2(Ap.x + Bp.y, Bp.x - Ap.y);
        }
    }
    __syncthreads();

    dit_stage<1,   0, false>(buf, tw, t); __syncthreads();
    dit_stage<8,   6, true >(buf, tw, t); __syncthreads();
    dit_stage<64,  3, true >(buf, tw, t); __syncthreads();
    dit_stage<512, 0, true >(buf, tw, t); __syncthreads();

    {
        const float sc = 1.0f / 4096.0f;
        int n = t << 3;
        float2 z0 = buf[IX(n+0)], z1 = buf[IX(n+1)], z2 = buf[IX(n+2)], z3 = buf[IX(n+3)];
        float2 z4 = buf[IX(n+4)], z5 = buf[IX(n+5)], z6 = buf[IX(n+6)], z7 = buf[IX(n+7)];
        uint4 oa, ob;
        oa.x = pk2(z0.x*sc, z1.x*sc); oa.y = pk2(z2.x*sc, z3.x*sc);
        oa.z = pk2(z4.x*sc, z5.x*sc); oa.w = pk2(z6.x*sc, z7.x*sc);
        ob.x = pk2(z0.y*sc, z1.y*sc); ob.y = pk2(z2.y*sc, z3.y*sc);
        ob.z = pk2(z4.y*sc, z5.y*sc); ob.w = pk2(z6.y*sc, z7.y*sc);
        ((uint4*)xs)[t] = oa;
        ((uint4*)xs)[t + 512] = ob;
    }
}

// ---------------- K7: wide transpose back to (B,N,D), fp16 -> fp32 ----------------
// 1024 blocks x 512 threads; block: 64 d x 256 n
__global__ __launch_bounds__(512) void k_transout(const ushort_t* __restrict__ xt,
                                                  float* __restrict__ out) {
    __shared__ uint_t tile[64 * 133];           // ~34 KB
    int bid = blockIdx.x;
    int b = bid >> 8;
    int rem = bid & 255;
    int nt = rem >> 4;
    int dt = rem & 15;
    int n0 = nt << 8, d0 = dt << 6;
    int t = threadIdx.x;
    const ushort_t* base = xt + ((size_t)(b * 1024 + d0)) * 4096 + n0;
    #pragma unroll
    for (int p = 0; p < 4; p++) {
        int d = (p << 4) + (t >> 5);             // 4 x 16 = 64 d
        int nc = (t & 31) << 3;
        uint4 v = *(const uint4*)(base + (size_t)d * 4096 + nc);
        uint_t* dst = tile + d * 133 + (nc >> 1);
        dst[0] = v.x; dst[1] = v.y; dst[2] = v.z; dst[3] = v.w;
    }
    __syncthreads();
    int d = t & 63;
    int nq = t >> 6;                             // 0..7
    float* ob = out + ((size_t)b * N_ + n0) * D_ + d0 + d;
    #pragma unroll 4
    for (int i = 0; i < 32; i++) {
        int n = (i << 3) + nq;
        uint_t w = tile[d * 133 + (n >> 1)];
        float v = (n & 1) ? hi_f(w) : lo_f(w);
        ob[(size_t)n * D_] = v;
    }
}

extern "C" void kernel_launch(void* const* d_in, const int* in_sizes, int n_in,
                              void* d_out, int out_size, void* d_ws, size_t ws_size,
                              hipStream_t stream) {
    const float* x     = (const float*)d_in[0];
    const float* lnw   = (const float*)d_in[1];
    const float* lnb   = (const float*)d_in[2];
    const float* bfilt = (const float*)d_in[3];
    const float* bbias = (const float*)d_in[4];
    const float* w0    = (const float*)d_in[5];
    const float* b0    = (const float*)d_in[6];
    const float* w1    = (const float*)d_in[7];
    const float* b1    = (const float*)d_in[8];
    const float* w2    = (const float*)d_in[9];
    const float* b2    = (const float*)d_in[10];

    float* ws = (float*)d_ws;
    ushort_t* xt   = (ushort_t*)ws;                       // 16,777,216 fp16
    float*  cpart  = ws + 8388608;                        // 524,288
    float*  pA     = ws + 8912896;                        // 16384
    float*  pB     = ws + 8929280;                        // 16384
    float*  p3     = ws + 8945664;                        // 2,098,176
    float2* eff    = (float2*)(ws + 11043840);            // 131,136 float2
    float*  out    = (float*)d_out;

    k_normT     <<<512,  512, 0, stream>>>(x, lnw, lnb, xt, cpart);
    k_mlp_part  <<<dim3(16, 4), 256, 0, stream>>>(cpart, w0, pA);
    k_mlp_part2 <<<dim3(16, 4), 256, 0, stream>>>(pA, b0, w1, pB);
    k_adapt_part<<<dim3(65, 8), 256, 0, stream>>>(pB, b1, w2, p3);
    k_eff       <<<129,  256, 0, stream>>>(p3, b2, bfilt, bbias, eff);
    k_fftmod    <<<2048, 512, 0, stream>>>(xt, eff);
    k_transout  <<<1024, 512, 0, stream>>>(xt, out);
}

// Round 9
// 222.962 us; speedup vs baseline: 1.0665x; 1.0665x over previous
//
#include <hip/hip_runtime.h>
#include <hip/hip_fp16.h>
#include <math.h>

#define B_ 4
#define N_ 4096
#define D_ 1024
#define H_ 16
#define HD_ 64
#define FB_ 2049

typedef unsigned short ushort_t;
typedef unsigned int uint_t;

__device__ __forceinline__ float2 cmul(float2 a, float2 b) {
    return make_float2(a.x*b.x - a.y*b.y, a.x*b.y + a.y*b.x);
}
__device__ __forceinline__ float2 cadd(float2 a, float2 b){return make_float2(a.x+b.x,a.y+b.y);}
__device__ __forceinline__ float2 csub(float2 a, float2 b){return make_float2(a.x-b.x,a.y-b.y);}
__device__ __forceinline__ float2 cconj(float2 a){return make_float2(a.x,-a.y);}
__device__ __forceinline__ float2 addi(float2 a, float2 b){return make_float2(a.x-b.y, a.y+b.x);}
__device__ __forceinline__ float2 subi(float2 a, float2 b){return make_float2(a.x+b.y, a.y-b.x);}

__device__ __forceinline__ float gelu_t(float m) {
    float u = 0.7978845608028654f * (m + 0.044715f * m * m * m);
    float e = __expf(-2.0f * u);
    float th = (1.0f - e) / (1.0f + e);
    return 0.5f * m * (1.0f + th);
}
__device__ __forceinline__ float2 cact(float2 z) {
    float m = sqrtf(z.x*z.x + z.y*z.y);
    float s = gelu_t(m) / (m + 1e-6f);
    return make_float2(z.x*s, z.y*s);
}

__device__ __forceinline__ ushort_t f2h(float f) {
    __half h = __float2half_rn(f);
    return *reinterpret_cast<ushort_t*>(&h);
}
__device__ __forceinline__ float h2f(ushort_t u) {
    __half h = *reinterpret_cast<__half*>(&u);
    return __half2float(h);
}
__device__ __forceinline__ uint_t pk2(float a, float b) {
    return (uint_t)f2h(a) | ((uint_t)f2h(b) << 16);
}
__device__ __forceinline__ float lo_f(uint_t u){ return h2f((ushort_t)(u & 0xffffu)); }
__device__ __forceinline__ float hi_f(uint_t u){ return h2f((ushort_t)(u >> 16)); }

// skewed LDS index
#define IX(e) ((e) + ((e) >> 4))

// base-8 digit reversal of a 12-bit index
__device__ __forceinline__ int rev12(int p) {
    return ((p & 7) << 9) | (((p >> 3) & 7) << 6) | (((p >> 6) & 7) << 3) | ((p >> 9) & 7);
}

// ---------------- K1: fused LN stats + apply + transpose (fp16 xt) + cpart ----------------
// 1024 blocks x 256 threads; block = 16 rows; XCD pair-swizzle keeps 64B lines co-XCD
__global__ __launch_bounds__(256) void k_normT(const float* __restrict__ x,
                                               const float* __restrict__ lnw,
                                               const float* __restrict__ lnb,
                                               ushort_t* __restrict__ xt,
                                               float* __restrict__ cpart) {
    __shared__ ushort_t lds16[16 * 1032];       // 33 KB; rows stride 516 uints
    uint_t* lds32 = (uint_t*)lds16;
    // swizzle: blocks m and m+8 handle chunk pair (2c, 2c+1) on the same XCD
    int m = blockIdx.x;
    int xcd = m & 7, q = m >> 3;
    int P = xcd * 64 + (q >> 1);                 // 0..511
    int b = P >> 7;
    int chunk = ((P & 127) << 1) + (q & 1);      // 0..255
    int n0 = chunk << 4;
    int lane = threadIdx.x & 63, w = threadIdx.x >> 6;   // 4 waves
    const float4* lw4 = (const float4*)lnw;
    const float4* lb4 = (const float4*)lnb;
    float4 W0 = lw4[lane], W1 = lw4[lane+64], W2 = lw4[lane+128], W3 = lw4[lane+192];
    float4 G0 = lb4[lane], G1 = lb4[lane+64], G2 = lb4[lane+128], G3 = lb4[lane+192];

    for (int j = 0; j < 4; j++) {
        int r = (w << 2) + j;                    // 16 rows
        const float4* xr = (const float4*)(x + ((size_t)b * N_ + n0 + r) * D_);
        float4 v0 = xr[lane], v1 = xr[lane+64], v2 = xr[lane+128], v3 = xr[lane+192];
        float s = v0.x+v0.y+v0.z+v0.w + v1.x+v1.y+v1.z+v1.w
                + v2.x+v2.y+v2.z+v2.w + v3.x+v3.y+v3.z+v3.w;
        float q2 = v0.x*v0.x+v0.y*v0.y+v0.z*v0.z+v0.w*v0.w
                 + v1.x*v1.x+v1.y*v1.y+v1.z*v1.z+v1.w*v1.w
                 + v2.x*v2.x+v2.y*v2.y+v2.z*v2.z+v2.w*v2.w
                 + v3.x*v3.x+v3.y*v3.y+v3.z*v3.z+v3.w*v3.w;
        for (int o = 1; o < 64; o <<= 1) { s += __shfl_xor(s, o); q2 += __shfl_xor(q2, o); }
        float mu = s * (1.0f / D_);
        float rstd = rsqrtf(q2 * (1.0f / D_) - mu * mu + 1e-5f);
        int base = r * 516 + 2 * lane;
        lds32[base]       = pk2((v0.x-mu)*rstd*W0.x+G0.x, (v0.y-mu)*rstd*W0.y+G0.y);
        lds32[base + 1]   = pk2((v0.z-mu)*rstd*W0.z+G0.z, (v0.w-mu)*rstd*W0.w+G0.w);
        lds32[base + 128] = pk2((v1.x-mu)*rstd*W1.x+G1.x, (v1.y-mu)*rstd*W1.y+G1.y);
        lds32[base + 129] = pk2((v1.z-mu)*rstd*W1.z+G1.z, (v1.w-mu)*rstd*W1.w+G1.w);
        lds32[base + 256] = pk2((v2.x-mu)*rstd*W2.x+G2.x, (v2.y-mu)*rstd*W2.y+G2.y);
        lds32[base + 257] = pk2((v2.z-mu)*rstd*W2.z+G2.z, (v2.w-mu)*rstd*W2.w+G2.w);
        lds32[base + 384] = pk2((v3.x-mu)*rstd*W3.x+G3.x, (v3.y-mu)*rstd*W3.y+G3.y);
        lds32[base + 385] = pk2((v3.z-mu)*rstd*W3.z+G3.z, (v3.w-mu)*rstd*W3.w+G3.w);
    }
    __syncthreads();
    for (int half = 0; half < 2; half++) {
        int dp = threadIdx.x + (half << 8);      // 0..511 (uint column = d-pair)
        float cs_e = 0.f, cs_o = 0.f;
        uint_t ce[8], co[8];
        #pragma unroll
        for (int i = 0; i < 8; i++) {
            uint_t w0 = lds32[(2*i) * 516 + dp];
            uint_t w1 = lds32[(2*i+1) * 516 + dp];
            ce[i] = (w0 & 0xffffu) | (w1 << 16);
            co[i] = (w0 >> 16) | (w1 & 0xffff0000u);
            cs_e += lo_f(w0) + lo_f(w1);
            cs_o += hi_f(w0) + hi_f(w1);
        }
        int de = dp * 2;
        uint4* dste = (uint4*)(xt + ((size_t)(b * 1024 + de)) * 4096 + n0);
        dste[0] = make_uint4(ce[0], ce[1], ce[2], ce[3]);
        dste[1] = make_uint4(ce[4], ce[5], ce[6], ce[7]);
        uint4* dsto = (uint4*)(xt + ((size_t)(b * 1024 + de + 1)) * 4096 + n0);
        dsto[0] = make_uint4(co[0], co[1], co[2], co[3]);
        dsto[1] = make_uint4(co[4], co[5], co[6], co[7]);
        ((float2*)(cpart + ((size_t)(b * 256 + chunk)) * D_))[dp] = make_float2(cs_e, cs_o);
    }
}

// ---------------- K2: finalize context ----------------
__global__ __launch_bounds__(256) void k_ctx(const float* __restrict__ cpart,
                                             float* __restrict__ ctx) {
    int id = blockIdx.x * 256 + threadIdx.x;    // 4096 = B*D
    int b = id >> 10, d = id & 1023;
    float s = 0.f;
    const float* p = cpart + (size_t)b * 256 * D_ + d;
    #pragma unroll 8
    for (int g = 0; g < 256; g++) s += p[g * D_];
    ctx[id] = s * (1.0f / N_);
}

// ---------------- K3: layer-0 partial GEMM ----------------
__global__ __launch_bounds__(256) void k_mlp_part(const float* __restrict__ in,
                                                  const float* __restrict__ w,
                                                  float* __restrict__ part) {
    __shared__ float li[4 * 256];
    int ks = blockIdx.y;
    for (int i = threadIdx.x; i < 1024; i += 256) {
        int b = i >> 8, kk = i & 255;
        li[i] = in[b * 1024 + ks * 256 + kk];
    }
    __syncthreads();
    int col = blockIdx.x * 64 + (threadIdx.x & 63);
    int b = threadIdx.x >> 6;
    const float* wp = w + (size_t)(ks * 256) * 1024 + col;
    const float* ip = li + b * 256;
    float acc = 0.f;
    #pragma unroll 8
    for (int k = 0; k < 256; k++) acc = fmaf(ip[k], wp[(size_t)k * 1024], acc);
    part[((size_t)ks * 4 + b) * 1024 + col] = acc;
}

// ---------------- K4: layer-1 partial GEMM ----------------
__global__ __launch_bounds__(256) void k_mlp_part2(const float* __restrict__ part,
                                                   const float* __restrict__ bias,
                                                   const float* __restrict__ w,
                                                   float* __restrict__ part2) {
    __shared__ float li[4 * 256];
    int ks = blockIdx.y;
    for (int i = threadIdx.x; i < 1024; i += 256) {
        int b = i >> 8, kk = (i & 255) + ks * 256;
        float v = part[b * 1024 + kk] + part[4096 + b * 1024 + kk] +
                  part[8192 + b * 1024 + kk] + part[12288 + b * 1024 + kk] + bias[kk];
        li[i] = fmaxf(v, 0.f);
    }
    __syncthreads();
    int col = blockIdx.x * 64 + (threadIdx.x & 63);
    int b = threadIdx.x >> 6;
    const float* wp = w + (size_t)(ks * 256) * 1024 + col;
    const float* ip = li + b * 256;
    float acc = 0.f;
    #pragma unroll 8
    for (int k = 0; k < 256; k++) acc = fmaf(ip[k], wp[(size_t)k * 1024], acc);
    part2[((size_t)ks * 4 + b) * 1024 + col] = acc;
}

// ---------------- K5: w2 partial GEMM ----------------
__global__ __launch_bounds__(256) void k_adapt_part(const float* __restrict__ part2,
                                                    const float* __restrict__ b1,
                                                    const float* __restrict__ w2,
                                                    float* __restrict__ part3) {
    __shared__ float lh[4 * 128];
    int ks = blockIdx.y;
    for (int i = threadIdx.x; i < 512; i += 256) {
        int b = i >> 7, kk = (i & 127) + ks * 128;
        float v = part2[b * 1024 + kk] + part2[4096 + b * 1024 + kk] +
                  part2[8192 + b * 1024 + kk] + part2[12288 + b * 1024 + kk] + b1[kk];
        lh[i] = fmaxf(v, 0.f);
    }
    __syncthreads();
    int j4 = blockIdx.x * 1024 + threadIdx.x * 4;
    if (j4 < 65568) {
        float a0x=0,a0y=0,a0z=0,a0w=0, a1x=0,a1y=0,a1z=0,a1w=0;
        float a2x=0,a2y=0,a2z=0,a2w=0, a3x=0,a3y=0,a3z=0,a3w=0;
        const float* wp = w2 + (size_t)(ks * 128) * 65568 + j4;
        #pragma unroll 4
        for (int k = 0; k < 128; k++) {
            float4 wv = *(const float4*)(wp + (size_t)k * 65568);
            float h0 = lh[k], h1 = lh[128 + k], h2 = lh[256 + k], h3 = lh[384 + k];
            a0x = fmaf(h0, wv.x, a0x); a0y = fmaf(h0, wv.y, a0y);
            a0z = fmaf(h0, wv.z, a0z); a0w = fmaf(h0, wv.w, a0w);
            a1x = fmaf(h1, wv.x, a1x); a1y = fmaf(h1, wv.y, a1y);
            a1z = fmaf(h1, wv.z, a1z); a1w = fmaf(h1, wv.w, a1w);
            a2x = fmaf(h2, wv.x, a2x); a2y = fmaf(h2, wv.y, a2y);
            a2z = fmaf(h2, wv.z, a2z); a2w = fmaf(h2, wv.w, a2w);
            a3x = fmaf(h3, wv.x, a3x); a3y = fmaf(h3, wv.y, a3y);
            a3z = fmaf(h3, wv.z, a3z); a3w = fmaf(h3, wv.w, a3w);
        }
        float* p3 = part3 + (size_t)ks * 4 * 65568 + j4;
        *(float4*)(p3)              = make_float4(a0x, a0y, a0z, a0w);
        *(float4*)(p3 + 65568)      = make_float4(a1x, a1y, a1z, a1w);
        *(float4*)(p3 + 2 * 65568)  = make_float4(a2x, a2y, a2z, a2w);
        *(float4*)(p3 + 3 * 65568)  = make_float4(a3x, a3y, a3z, a3w);
    }
}

// ---------------- K6: finalize adapt -> effective filter/bias ----------------
__global__ __launch_bounds__(256) void k_eff(const float* __restrict__ part3,
                                             const float* __restrict__ b2,
                                             const float* __restrict__ bfilt,
                                             const float* __restrict__ bbias,
                                             float2* __restrict__ eff) {
    int p = blockIdx.x * 256 + threadIdx.x;     // 32784 = H*FB
    if (p >= 32784) return;
    int h = p / 2049, f = p % 2049;
    float bf = bfilt[p], bb = bbias[p];
    float sc0 = b2[2 * p], bi0 = b2[2 * p + 1];
    #pragma unroll
    for (int b = 0; b < 4; b++) {
        float sc = sc0, bi = bi0;
        #pragma unroll
        for (int s = 0; s < 8; s++) {
            const float* q = part3 + ((size_t)s * 4 + b) * 65568 + 2 * p;
            sc += q[0]; bi += q[1];
        }
        eff[((size_t)b * H_ + h) * FB_ + f] = make_float2(bf * (1.0f + sc), bb + bi);
    }
}

// ---------------- in-place radix-8 DIF / DIT stages (serial-chain twiddles, R6) ----------
template<int M, int SH, bool TW>
__device__ __forceinline__ void dif_stage(float2* buf, const float2* tw, int t) {
    const float s2 = 0.70710678118654752f;
    int j = t & (M - 1);
    int base = 8 * t - 7 * j;
    float2 u0 = buf[IX(base)];
    float2 u1 = buf[IX(base + M)];
    float2 u2 = buf[IX(base + 2*M)];
    float2 u3 = buf[IX(base + 3*M)];
    float2 u4 = buf[IX(base + 4*M)];
    float2 u5 = buf[IX(base + 5*M)];
    float2 u6 = buf[IX(base + 6*M)];
    float2 u7 = buf[IX(base + 7*M)];
    float2 a0 = cadd(u0,u4), a1 = csub(u0,u4), a2 = cadd(u2,u6), a3 = csub(u2,u6);
    float2 E0 = cadd(a0,a2), E1 = subi(a1,a3), E2 = csub(a0,a2), E3 = addi(a1,a3);
    float2 c0 = cadd(u1,u5), c1 = csub(u1,u5), c2 = cadd(u3,u7), c3 = csub(u3,u7);
    float2 O0 = cadd(c0,c2), O1 = subi(c1,c3), O2 = csub(c0,c2), O3 = addi(c1,c3);
    float2 R1 = make_float2(s2*(O1.x + O1.y), s2*(O1.y - O1.x));
    float2 R2 = make_float2(O2.y, -O2.x);
    float2 R3 = make_float2(s2*(O3.y - O3.x), -s2*(O3.x + O3.y));
    float2 X0 = cadd(E0,O0), X4 = csub(E0,O0);
    float2 X1 = cadd(E1,R1), X5 = csub(E1,R1);
    float2 X2 = cadd(E2,R2), X6 = csub(E2,R2);
    float2 X3 = cadd(E3,R3), X7 = csub(E3,R3);
    buf[IX(base)] = X0;
    if (TW) {
        float2 w1 = tw[IX(j << SH)];
        float2 w = w1;
        buf[IX(base + M)]   = cmul(w, X1); w = cmul(w, w1);
        buf[IX(base + 2*M)] = cmul(w, X2); w = cmul(w, w1);
        buf[IX(base + 3*M)] = cmul(w, X3); w = cmul(w, w1);
        buf[IX(base + 4*M)] = cmul(w, X4); w = cmul(w, w1);
        buf[IX(base + 5*M)] = cmul(w, X5); w = cmul(w, w1);
        buf[IX(base + 6*M)] = cmul(w, X6); w = cmul(w, w1);
        buf[IX(base + 7*M)] = cmul(w, X7);
    } else {
        buf[IX(base + M)]   = X1;
        buf[IX(base + 2*M)] = X2;
        buf[IX(base + 3*M)] = X3;
        buf[IX(base + 4*M)] = X4;
        buf[IX(base + 5*M)] = X5;
        buf[IX(base + 6*M)] = X6;
        buf[IX(base + 7*M)] = X7;
    }
}

template<int M, int SH, bool TW>
__device__ __forceinline__ void dit_stage(float2* buf, const float2* tw, int t) {
    const float s2 = 0.70710678118654752f;
    int j = t & (M - 1);
    int base = 8 * t - 7 * j;
    float2 u0 = buf[IX(base)];
    float2 u1, u2, u3, u4, u5, u6, u7;
    if (TW) {
        float2 w1 = cconj(tw[IX(j << SH)]);
        float2 w = w1;
        u1 = cmul(w, buf[IX(base + M)]);   w = cmul(w, w1);
        u2 = cmul(w, buf[IX(base + 2*M)]); w = cmul(w, w1);
        u3 = cmul(w, buf[IX(base + 3*M)]); w = cmul(w, w1);
        u4 = cmul(w, buf[IX(base + 4*M)]); w = cmul(w, w1);
        u5 = cmul(w, buf[IX(base + 5*M)]); w = cmul(w, w1);
        u6 = cmul(w, buf[IX(base + 6*M)]); w = cmul(w, w1);
        u7 = cmul(w, buf[IX(base + 7*M)]);
    } else {
        u1 = buf[IX(base + M)];
        u2 = buf[IX(base + 2*M)];
        u3 = buf[IX(base + 3*M)];
        u4 = buf[IX(base + 4*M)];
        u5 = buf[IX(base + 5*M)];
        u6 = buf[IX(base + 6*M)];
        u7 = buf[IX(base + 7*M)];
    }
    float2 a0 = cadd(u0,u4), a1 = csub(u0,u4), a2 = cadd(u2,u6), a3 = csub(u2,u6);
    float2 E0 = cadd(a0,a2), E1 = addi(a1,a3), E2 = csub(a0,a2), E3 = subi(a1,a3);
    float2 c0 = cadd(u1,u5), c1 = csub(u1,u5), c2 = cadd(u3,u7), c3 = csub(u3,u7);
    float2 O0 = cadd(c0,c2), O1 = addi(c1,c3), O2 = csub(c0,c2), O3 = subi(c1,c3);
    float2 R1 = make_float2(s2*(O1.x - O1.y),  s2*(O1.x + O1.y));
    float2 R2 = make_float2(-O2.y, O2.x);
    float2 R3 = make_float2(-s2*(O3.x + O3.y), s2*(O3.x - O3.y));
    buf[IX(base)]       = cadd(E0,O0);
    buf[IX(base + 4*M)] = csub(E0,O0);
    buf[IX(base + M)]   = cadd(E1,R1);
    buf[IX(base + 5*M)] = csub(E1,R1);
    buf[IX(base + 2*M)] = cadd(E2,R2);
    buf[IX(base + 6*M)] = csub(E2,R2);
    buf[IX(base + 3*M)] = cadd(E3,R3);
    buf[IX(base + 7*M)] = csub(E3,R3);
}

// ---------------- K7: in-place FFT + mod + iFFT, fp16 xt ----------------
__global__ __launch_bounds__(512, 6) void k_fftmod(ushort_t* __restrict__ xt,
                                                   const float2* __restrict__ eff) {
    __shared__ float2 buf[4352];                // 4096 skewed
    __shared__ float2 tw[544];                  // W_4096^e, e<512, skewed
    int t = threadIdx.x;
    int sig0 = blockIdx.x * 2;                  // 2048 blocks
    int b = sig0 >> 10;
    int h = (sig0 & 1023) >> 6;
    const float2* ef = eff + ((size_t)b * H_ + h) * FB_;
    ushort_t* xs = xt + (size_t)sig0 * 4096;

    {
        float sv, cv;
        __sincosf(-(float)M_PI * (float)t * (1.0f / 2048.0f), &sv, &cv);
        tw[IX(t)] = make_float2(cv, sv);
    }
    {
        const uint4* pa = (const uint4*)xs;
        const uint4* pb = pa + 512;
        uint4 ua = pa[t], ub = pb[t];
        int n = t << 3;
        buf[IX(n+0)] = make_float2(lo_f(ua.x), lo_f(ub.x));
        buf[IX(n+1)] = make_float2(hi_f(ua.x), hi_f(ub.x));
        buf[IX(n+2)] = make_float2(lo_f(ua.y), lo_f(ub.y));
        buf[IX(n+3)] = make_float2(hi_f(ua.y), hi_f(ub.y));
        buf[IX(n+4)] = make_float2(lo_f(ua.z), lo_f(ub.z));
        buf[IX(n+5)] = make_float2(hi_f(ua.z), hi_f(ub.z));
        buf[IX(n+6)] = make_float2(lo_f(ua.w), lo_f(ub.w));
        buf[IX(n+7)] = make_float2(hi_f(ua.w), hi_f(ub.w));
    }
    __syncthreads();

    dif_stage<512, 0, true >(buf, tw, t); __syncthreads();
    dif_stage<64,  3, true >(buf, tw, t); __syncthreads();
    dif_stage<8,   6, true >(buf, tw, t); __syncthreads();
    dif_stage<1,   0, false>(buf, tw, t); __syncthreads();

    if (t == 0) {                                // k = 0 at p = 0
        float2 Z = buf[IX(0)];
        float2 e0 = ef[0];
        float Av = Z.x * e0.x + e0.y;
        float Bv = Z.y * e0.x + e0.y;
        float ma = fabsf(Av); Av *= gelu_t(ma) / (ma + 1e-6f);
        float mb = fabsf(Bv); Bv *= gelu_t(mb) / (mb + 1e-6f);
        buf[IX(0)] = make_float2(Av, Bv);
    }
    #pragma unroll
    for (int ii = 0; ii < 4; ii++) {
        int k = 1 + t + (ii << 9);               // 1..2048
        if (k == 2048) {                         // Nyquist at p = rev(2048) = 4
            float2 Z = buf[IX(4)];
            float2 eN = ef[2048];
            float Av = Z.x * eN.x + eN.y;
            float Bv = Z.y * eN.x + eN.y;
            float ma = fabsf(Av); Av *= gelu_t(ma) / (ma + 1e-6f);
            float mb = fabsf(Bv); Bv *= gelu_t(mb) / (mb + 1e-6f);
            buf[IX(4)] = make_float2(Av, Bv);
        } else {
            int pk = rev12(k);
            int pq = rev12(4096 - k);
            float2 Zk = buf[IX(pk)], Zq = buf[IX(pq)];
            float2 A  = make_float2(0.5f*(Zk.x + Zq.x), 0.5f*(Zk.y - Zq.y));
            float2 Bc = make_float2(0.5f*(Zk.y + Zq.y), 0.5f*(Zq.x - Zk.x));
            float2 e = ef[k];
            float2 Ap = make_float2(A.x * e.x + e.y,  A.y * e.x);
            float2 Bp = make_float2(Bc.x * e.x + e.y, Bc.y * e.x);
            Ap = cact(Ap); Bp = cact(Bp);
            buf[IX(pk)] = make_float2(Ap.x - Bp.y, Ap.y + Bp.x);
            buf[IX(pq)] = make_float2(Ap.x + Bp.y, Bp.x - Ap.y);
        }
    }
    __syncthreads();

    dit_stage<1,   0, false>(buf, tw, t); __syncthreads();
    dit_stage<8,   6, true >(buf, tw, t); __syncthreads();
    dit_stage<64,  3, true >(buf, tw, t); __syncthreads();
    dit_stage<512, 0, true >(buf, tw, t); __syncthreads();

    {
        const float sc = 1.0f / 4096.0f;
        int n = t << 3;
        float2 z0 = buf[IX(n+0)], z1 = buf[IX(n+1)], z2 = buf[IX(n+2)], z3 = buf[IX(n+3)];
        float2 z4 = buf[IX(n+4)], z5 = buf[IX(n+5)], z6 = buf[IX(n+6)], z7 = buf[IX(n+7)];
        uint4 oa, ob;
        oa.x = pk2(z0.x*sc, z1.x*sc); oa.y = pk2(z2.x*sc, z3.x*sc);
        oa.z = pk2(z4.x*sc, z5.x*sc); oa.w = pk2(z6.x*sc, z7.x*sc);
        ob.x = pk2(z0.y*sc, z1.y*sc); ob.y = pk2(z2.y*sc, z3.y*sc);
        ob.z = pk2(z4.y*sc, z5.y*sc); ob.w = pk2(z6.y*sc, z7.y*sc);
        ((uint4*)xs)[t] = oa;
        ((uint4*)xs)[t + 512] = ob;
    }
}

// ---------------- K8: transpose back to (B,N,D), fp16 -> fp32 (R6 version) ----------------
__global__ __launch_bounds__(256) void k_transout(const ushort_t* __restrict__ xt,
                                                  float* __restrict__ out) {
    __shared__ float tile[64 * 65];
    int bid = blockIdx.x;
    int b = bid >> 10;
    int rem = bid & 1023;
    int nt = rem >> 4;
    int dt = rem & 15;
    int n0 = nt << 6;
    int tx = threadIdx.x & 63, ty = threadIdx.x >> 6;
    const ushort_t* xtb = xt + ((size_t)((b * H_ + dt) * HD_)) * (size_t)N_ + n0;
    for (int r = 0; r < 16; r++) {
        int dloc = ty + 4 * r;
        tile[dloc * 65 + tx] = h2f(xtb[(size_t)dloc * N_ + tx]);
    }
    __syncthreads();
    float* ob = out + ((size_t)b * N_ + n0) * D_ + dt * HD_;
    for (int r = 0; r < 16; r++) {
        int nn = ty + 4 * r;
        ob[(size_t)nn * D_ + tx] = tile[tx * 65 + nn];
    }
}

extern "C" void kernel_launch(void* const* d_in, const int* in_sizes, int n_in,
                              void* d_out, int out_size, void* d_ws, size_t ws_size,
                              hipStream_t stream) {
    const float* x     = (const float*)d_in[0];
    const float* lnw   = (const float*)d_in[1];
    const float* lnb   = (const float*)d_in[2];
    const float* bfilt = (const float*)d_in[3];
    const float* bbias = (const float*)d_in[4];
    const float* w0    = (const float*)d_in[5];
    const float* b0    = (const float*)d_in[6];
    const float* w1    = (const float*)d_in[7];
    const float* b1    = (const float*)d_in[8];
    const float* w2    = (const float*)d_in[9];
    const float* b2    = (const float*)d_in[10];

    float* ws = (float*)d_ws;
    ushort_t* xt   = (ushort_t*)ws;                       // 16,777,216 fp16
    float*  cpart  = ws + 8388608;                        // 1,048,576
    float*  ctx    = ws + 9437184;                        // 4096
    float*  pA     = ws + 9441280;                        // 16384
    float*  pB     = ws + 9457664;                        // 16384
    float*  p3     = ws + 9474048;                        // 2,098,176
    float2* eff    = (float2*)(ws + 11572224);            // 131,136 float2
    float*  out    = (float*)d_out;

    k_normT     <<<1024, 256, 0, stream>>>(x, lnw, lnb, xt, cpart);
    k_ctx       <<<16,   256, 0, stream>>>(cpart, ctx);
    k_mlp_part  <<<dim3(16, 4), 256, 0, stream>>>(ctx, w0, pA);
    k_mlp_part2 <<<dim3(16, 4), 256, 0, stream>>>(pA, b0, w1, pB);
    k_adapt_part<<<dim3(65, 8), 256, 0, stream>>>(pB, b1, w2, p3);
    k_eff       <<<129,  256, 0, stream>>>(p3, b2, bfilt, bbias, eff);
    k_fftmod    <<<2048, 512, 0, stream>>>(xt, eff);
    k_transout  <<<4096, 256, 0, stream>>>(xt, out);
}

// Round 10
// 183.124 us; speedup vs baseline: 1.2986x; 1.2175x over previous
//
#include <hip/hip_runtime.h>
#include <hip/hip_fp16.h>
#include <math.h>

#define B_ 4
#define N_ 4096
#define D_ 1024
#define H_ 16
#define HD_ 64
#define FB_ 2049

typedef unsigned short ushort_t;
typedef unsigned int uint_t;

__device__ __forceinline__ float2 cmul(float2 a, float2 b) {
    return make_float2(a.x*b.x - a.y*b.y, a.x*b.y + a.y*b.x);
}
__device__ __forceinline__ float2 cadd(float2 a, float2 b){return make_float2(a.x+b.x,a.y+b.y);}
__device__ __forceinline__ float2 csub(float2 a, float2 b){return make_float2(a.x-b.x,a.y-b.y);}
__device__ __forceinline__ float2 cconj(float2 a){return make_float2(a.x,-a.y);}
__device__ __forceinline__ float2 addi(float2 a, float2 b){return make_float2(a.x-b.y, a.y+b.x);}
__device__ __forceinline__ float2 subi(float2 a, float2 b){return make_float2(a.x+b.y, a.y-b.x);}

__device__ __forceinline__ float gelu_t(float m) {
    float u = 0.7978845608028654f * (m + 0.044715f * m * m * m);
    float e = __expf(-2.0f * u);
    float th = (1.0f - e) / (1.0f + e);
    return 0.5f * m * (1.0f + th);
}
__device__ __forceinline__ float2 cact(float2 z) {
    float m = sqrtf(z.x*z.x + z.y*z.y);
    float s = gelu_t(m) / (m + 1e-6f);
    return make_float2(z.x*s, z.y*s);
}

__device__ __forceinline__ ushort_t f2h(float f) {
    __half h = __float2half_rn(f);
    return *reinterpret_cast<ushort_t*>(&h);
}
__device__ __forceinline__ float h2f(ushort_t u) {
    __half h = *reinterpret_cast<__half*>(&u);
    return __half2float(h);
}
__device__ __forceinline__ uint_t pk2(float a, float b) {
    return (uint_t)f2h(a) | ((uint_t)f2h(b) << 16);
}
__device__ __forceinline__ float lo_f(uint_t u){ return h2f((ushort_t)(u & 0xffffu)); }
__device__ __forceinline__ float hi_f(uint_t u){ return h2f((ushort_t)(u >> 16)); }

// skewed LDS index
#define IX(e) ((e) + ((e) >> 4))

// base-8 digit reversal of a 12-bit index
__device__ __forceinline__ int rev12(int p) {
    return ((p & 7) << 9) | (((p >> 3) & 7) << 6) | (((p >> 6) & 7) << 3) | ((p >> 9) & 7);
}

// ---------------- K1: fused LayerNorm stats + apply + transpose (fp16 xt) + cpart --------
// R6-measured version: 512 blocks x 256 threads, 32 rows/block
__global__ __launch_bounds__(256) void k_normT(const float* __restrict__ x,
                                               const float* __restrict__ lnw,
                                               const float* __restrict__ lnb,
                                               ushort_t* __restrict__ xt,
                                               float* __restrict__ cpart) {
    __shared__ ushort_t lds16[32 * 1032];       // rows stride 516 uints
    uint_t* lds32 = (uint_t*)lds16;
    int blk = blockIdx.x;
    int b = blk >> 7, chunk = blk & 127;
    int n0 = chunk << 5;
    int lane = threadIdx.x & 63, w = threadIdx.x >> 6;
    const float4* lw4 = (const float4*)lnw;
    const float4* lb4 = (const float4*)lnb;
    float4 W0 = lw4[lane], W1 = lw4[lane+64], W2 = lw4[lane+128], W3 = lw4[lane+192];
    float4 G0 = lb4[lane], G1 = lb4[lane+64], G2 = lb4[lane+128], G3 = lb4[lane+192];

    for (int j = 0; j < 8; j++) {
        int r = (w << 3) + j;
        const float4* xr = (const float4*)(x + ((size_t)b * N_ + n0 + r) * D_);
        float4 v0 = xr[lane], v1 = xr[lane+64], v2 = xr[lane+128], v3 = xr[lane+192];
        float s = v0.x+v0.y+v0.z+v0.w + v1.x+v1.y+v1.z+v1.w
                + v2.x+v2.y+v2.z+v2.w + v3.x+v3.y+v3.z+v3.w;
        float q = v0.x*v0.x+v0.y*v0.y+v0.z*v0.z+v0.w*v0.w
                + v1.x*v1.x+v1.y*v1.y+v1.z*v1.z+v1.w*v1.w
                + v2.x*v2.x+v2.y*v2.y+v2.z*v2.z+v2.w*v2.w
                + v3.x*v3.x+v3.y*v3.y+v3.z*v3.z+v3.w*v3.w;
        for (int o = 1; o < 64; o <<= 1) { s += __shfl_xor(s, o); q += __shfl_xor(q, o); }
        float mu = s * (1.0f / D_);
        float rstd = rsqrtf(q * (1.0f / D_) - mu * mu + 1e-5f);
        int base = r * 516 + 2 * lane;
        lds32[base]       = pk2((v0.x-mu)*rstd*W0.x+G0.x, (v0.y-mu)*rstd*W0.y+G0.y);
        lds32[base + 1]   = pk2((v0.z-mu)*rstd*W0.z+G0.z, (v0.w-mu)*rstd*W0.w+G0.w);
        lds32[base + 128] = pk2((v1.x-mu)*rstd*W1.x+G1.x, (v1.y-mu)*rstd*W1.y+G1.y);
        lds32[base + 129] = pk2((v1.z-mu)*rstd*W1.z+G1.z, (v1.w-mu)*rstd*W1.w+G1.w);
        lds32[base + 256] = pk2((v2.x-mu)*rstd*W2.x+G2.x, (v2.y-mu)*rstd*W2.y+G2.y);
        lds32[base + 257] = pk2((v2.z-mu)*rstd*W2.z+G2.z, (v2.w-mu)*rstd*W2.w+G2.w);
        lds32[base + 384] = pk2((v3.x-mu)*rstd*W3.x+G3.x, (v3.y-mu)*rstd*W3.y+G3.y);
        lds32[base + 385] = pk2((v3.z-mu)*rstd*W3.z+G3.z, (v3.w-mu)*rstd*W3.w+G3.w);
    }
    __syncthreads();
    for (int half = 0; half < 2; half++) {
        int dp = threadIdx.x + (half << 8);      // 0..511
        float cs_e = 0.f, cs_o = 0.f;
        uint_t ce[16], co[16];
        #pragma unroll
        for (int i = 0; i < 16; i++) {
            uint_t w0 = lds32[(2*i) * 516 + dp];
            uint_t w1 = lds32[(2*i+1) * 516 + dp];
            ce[i] = (w0 & 0xffffu) | (w1 << 16);
            co[i] = (w0 >> 16) | (w1 & 0xffff0000u);
            cs_e += lo_f(w0) + lo_f(w1);
            cs_o += hi_f(w0) + hi_f(w1);
        }
        int de = dp * 2;
        uint4* dste = (uint4*)(xt + ((size_t)(b * 1024 + de)) * 4096 + n0);
        dste[0] = make_uint4(ce[0], ce[1], ce[2], ce[3]);
        dste[1] = make_uint4(ce[4], ce[5], ce[6], ce[7]);
        dste[2] = make_uint4(ce[8], ce[9], ce[10], ce[11]);
        dste[3] = make_uint4(ce[12], ce[13], ce[14], ce[15]);
        uint4* dsto = (uint4*)(xt + ((size_t)(b * 1024 + de + 1)) * 4096 + n0);
        dsto[0] = make_uint4(co[0], co[1], co[2], co[3]);
        dsto[1] = make_uint4(co[4], co[5], co[6], co[7]);
        dsto[2] = make_uint4(co[8], co[9], co[10], co[11]);
        dsto[3] = make_uint4(co[12], co[13], co[14], co[15]);
        ((float2*)(cpart + ((size_t)(b * 128 + chunk)) * D_))[dp] = make_float2(cs_e, cs_o);
    }
}

// ---------------- K2: finalize context ----------------
__global__ __launch_bounds__(256) void k_ctx(const float* __restrict__ cpart,
                                             float* __restrict__ ctx) {
    int id = blockIdx.x * 256 + threadIdx.x;    // 4096 = B*D
    int b = id >> 10, d = id & 1023;
    float s = 0.f;
    const float* p = cpart + (size_t)b * 128 * D_ + d;
    #pragma unroll 8
    for (int g = 0; g < 128; g++) s += p[g * D_];
    ctx[id] = s * (1.0f / N_);
}

// ---------------- K3: layer-0 partial GEMM, 16 K-slices (256 blocks) ----------------
__global__ __launch_bounds__(256) void k_mlp_part(const float* __restrict__ in,
                                                  const float* __restrict__ w,
                                                  float* __restrict__ part) {
    __shared__ float li[4 * 64];
    int ks = blockIdx.y;                         // 16 slices of 64
    if (threadIdx.x < 256) {
        int i = threadIdx.x;
        int b = i >> 6, kk = i & 63;
        li[i] = in[b * 1024 + ks * 64 + kk];
    }
    __syncthreads();
    int col = blockIdx.x * 64 + (threadIdx.x & 63);
    int b = threadIdx.x >> 6;
    const float* wp = w + (size_t)(ks * 64) * 1024 + col;
    const float* ip = li + b * 64;
    float a0 = 0.f, a1 = 0.f, a2 = 0.f, a3 = 0.f;
    #pragma unroll
    for (int k = 0; k < 64; k += 4) {
        a0 = fmaf(ip[k],     wp[(size_t)k * 1024],        a0);
        a1 = fmaf(ip[k + 1], wp[(size_t)(k + 1) * 1024],  a1);
        a2 = fmaf(ip[k + 2], wp[(size_t)(k + 2) * 1024],  a2);
        a3 = fmaf(ip[k + 3], wp[(size_t)(k + 3) * 1024],  a3);
    }
    part[((size_t)ks * 4 + b) * 1024 + col] = (a0 + a1) + (a2 + a3);
}

// ---------------- K4: layer-1 partial GEMM, 16 K-slices; reduces 16 layer-0 partials ----
__global__ __launch_bounds__(256) void k_mlp_part2(const float* __restrict__ part,
                                                   const float* __restrict__ bias,
                                                   const float* __restrict__ w,
                                                   float* __restrict__ part2) {
    __shared__ float li[4 * 64];
    int ks = blockIdx.y;
    if (threadIdx.x < 256) {
        int i = threadIdx.x;
        int b = i >> 6, kk = ks * 64 + (i & 63);
        float v = bias[kk];
        #pragma unroll
        for (int s = 0; s < 16; s++) v += part[((size_t)s * 4 + b) * 1024 + kk];
        li[i] = fmaxf(v, 0.f);
    }
    __syncthreads();
    int col = blockIdx.x * 64 + (threadIdx.x & 63);
    int b = threadIdx.x >> 6;
    const float* wp = w + (size_t)(ks * 64) * 1024 + col;
    const float* ip = li + b * 64;
    float a0 = 0.f, a1 = 0.f, a2 = 0.f, a3 = 0.f;
    #pragma unroll
    for (int k = 0; k < 64; k += 4) {
        a0 = fmaf(ip[k],     wp[(size_t)k * 1024],        a0);
        a1 = fmaf(ip[k + 1], wp[(size_t)(k + 1) * 1024],  a1);
        a2 = fmaf(ip[k + 2], wp[(size_t)(k + 2) * 1024],  a2);
        a3 = fmaf(ip[k + 3], wp[(size_t)(k + 3) * 1024],  a3);
    }
    part2[((size_t)ks * 4 + b) * 1024 + col] = (a0 + a1) + (a2 + a3);
}

// ---------------- K5: w2 partial GEMM; reduces 16 layer-1 partials ----------------
__global__ __launch_bounds__(256) void k_adapt_part(const float* __restrict__ part2,
                                                    const float* __restrict__ b1,
                                                    const float* __restrict__ w2,
                                                    float* __restrict__ part3) {
    __shared__ float lh[4 * 128];
    int ks = blockIdx.y;
    for (int i = threadIdx.x; i < 512; i += 256) {
        int b = i >> 7, kk = (i & 127) + ks * 128;
        float v = b1[kk];
        #pragma unroll
        for (int s = 0; s < 16; s++) v += part2[((size_t)s * 4 + b) * 1024 + kk];
        lh[i] = fmaxf(v, 0.f);
    }
    __syncthreads();
    int j4 = blockIdx.x * 1024 + threadIdx.x * 4;
    if (j4 < 65568) {
        float a0x=0,a0y=0,a0z=0,a0w=0, a1x=0,a1y=0,a1z=0,a1w=0;
        float a2x=0,a2y=0,a2z=0,a2w=0, a3x=0,a3y=0,a3z=0,a3w=0;
        const float* wp = w2 + (size_t)(ks * 128) * 65568 + j4;
        #pragma unroll 4
        for (int k = 0; k < 128; k++) {
            float4 wv = *(const float4*)(wp + (size_t)k * 65568);
            float h0 = lh[k], h1 = lh[128 + k], h2 = lh[256 + k], h3 = lh[384 + k];
            a0x = fmaf(h0, wv.x, a0x); a0y = fmaf(h0, wv.y, a0y);
            a0z = fmaf(h0, wv.z, a0z); a0w = fmaf(h0, wv.w, a0w);
            a1x = fmaf(h1, wv.x, a1x); a1y = fmaf(h1, wv.y, a1y);
            a1z = fmaf(h1, wv.z, a1z); a1w = fmaf(h1, wv.w, a1w);
            a2x = fmaf(h2, wv.x, a2x); a2y = fmaf(h2, wv.y, a2y);
            a2z = fmaf(h2, wv.z, a2z); a2w = fmaf(h2, wv.w, a2w);
            a3x = fmaf(h3, wv.x, a3x); a3y = fmaf(h3, wv.y, a3y);
            a3z = fmaf(h3, wv.z, a3z); a3w = fmaf(h3, wv.w, a3w);
        }
        float* p3 = part3 + (size_t)ks * 4 * 65568 + j4;
        *(float4*)(p3)              = make_float4(a0x, a0y, a0z, a0w);
        *(float4*)(p3 + 65568)      = make_float4(a1x, a1y, a1z, a1w);
        *(float4*)(p3 + 2 * 65568)  = make_float4(a2x, a2y, a2z, a2w);
        *(float4*)(p3 + 3 * 65568)  = make_float4(a3x, a3y, a3z, a3w);
    }
}

// ---------------- K6: finalize adapt -> effective filter/bias ----------------
__global__ __launch_bounds__(256) void k_eff(const float* __restrict__ part3,
                                             const float* __restrict__ b2,
                                             const float* __restrict__ bfilt,
                                             const float* __restrict__ bbias,
                                             float2* __restrict__ eff) {
    int p = blockIdx.x * 256 + threadIdx.x;     // 32784 = H*FB
    if (p >= 32784) return;
    int h = p / 2049, f = p % 2049;
    float bf = bfilt[p], bb = bbias[p];
    float sc0 = b2[2 * p], bi0 = b2[2 * p + 1];
    #pragma unroll
    for (int b = 0; b < 4; b++) {
        float sc = sc0, bi = bi0;
        #pragma unroll
        for (int s = 0; s < 8; s++) {
            const float* q = part3 + ((size_t)s * 4 + b) * 65568 + 2 * p;
            sc += q[0]; bi += q[1];
        }
        eff[((size_t)b * H_ + h) * FB_ + f] = make_float2(bf * (1.0f + sc), bb + bi);
    }
}

// ---------------- in-place radix-8 DIF / DIT stages (serial-chain twiddles) ----------
template<int M, int SH, bool TW>
__device__ __forceinline__ void dif_stage(float2* buf, const float2* tw, int t) {
    const float s2 = 0.70710678118654752f;
    int j = t & (M - 1);
    int base = 8 * t - 7 * j;
    float2 u0 = buf[IX(base)];
    float2 u1 = buf[IX(base + M)];
    float2 u2 = buf[IX(base + 2*M)];
    float2 u3 = buf[IX(base + 3*M)];
    float2 u4 = buf[IX(base + 4*M)];
    float2 u5 = buf[IX(base + 5*M)];
    float2 u6 = buf[IX(base + 6*M)];
    float2 u7 = buf[IX(base + 7*M)];
    float2 a0 = cadd(u0,u4), a1 = csub(u0,u4), a2 = cadd(u2,u6), a3 = csub(u2,u6);
    float2 E0 = cadd(a0,a2), E1 = subi(a1,a3), E2 = csub(a0,a2), E3 = addi(a1,a3);
    float2 c0 = cadd(u1,u5), c1 = csub(u1,u5), c2 = cadd(u3,u7), c3 = csub(u3,u7);
    float2 O0 = cadd(c0,c2), O1 = subi(c1,c3), O2 = csub(c0,c2), O3 = addi(c1,c3);
    float2 R1 = make_float2(s2*(O1.x + O1.y), s2*(O1.y - O1.x));
    float2 R2 = make_float2(O2.y, -O2.x);
    float2 R3 = make_float2(s2*(O3.y - O3.x), -s2*(O3.x + O3.y));
    float2 X0 = cadd(E0,O0), X4 = csub(E0,O0);
    float2 X1 = cadd(E1,R1), X5 = csub(E1,R1);
    float2 X2 = cadd(E2,R2), X6 = csub(E2,R2);
    float2 X3 = cadd(E3,R3), X7 = csub(E3,R3);
    buf[IX(base)] = X0;
    if (TW) {
        float2 w1 = tw[IX(j << SH)];
        float2 w = w1;
        buf[IX(base + M)]   = cmul(w, X1); w = cmul(w, w1);
        buf[IX(base + 2*M)] = cmul(w, X2); w = cmul(w, w1);
        buf[IX(base + 3*M)] = cmul(w, X3); w = cmul(w, w1);
        buf[IX(base + 4*M)] = cmul(w, X4); w = cmul(w, w1);
        buf[IX(base + 5*M)] = cmul(w, X5); w = cmul(w, w1);
        buf[IX(base + 6*M)] = cmul(w, X6); w = cmul(w, w1);
        buf[IX(base + 7*M)] = cmul(w, X7);
    } else {
        buf[IX(base + M)]   = X1;
        buf[IX(base + 2*M)] = X2;
        buf[IX(base + 3*M)] = X3;
        buf[IX(base + 4*M)] = X4;
        buf[IX(base + 5*M)] = X5;
        buf[IX(base + 6*M)] = X6;
        buf[IX(base + 7*M)] = X7;
    }
}

template<int M, int SH, bool TW>
__device__ __forceinline__ void dit_stage(float2* buf, const float2* tw, int t) {
    const float s2 = 0.70710678118654752f;
    int j = t & (M - 1);
    int base = 8 * t - 7 * j;
    float2 u0 = buf[IX(base)];
    float2 u1, u2, u3, u4, u5, u6, u7;
    if (TW) {
        float2 w1 = cconj(tw[IX(j << SH)]);
        float2 w = w1;
        u1 = cmul(w, buf[IX(base + M)]);   w = cmul(w, w1);
        u2 = cmul(w, buf[IX(base + 2*M)]); w = cmul(w, w1);
        u3 = cmul(w, buf[IX(base + 3*M)]); w = cmul(w, w1);
        u4 = cmul(w, buf[IX(base + 4*M)]); w = cmul(w, w1);
        u5 = cmul(w, buf[IX(base + 5*M)]); w = cmul(w, w1);
        u6 = cmul(w, buf[IX(base + 6*M)]); w = cmul(w, w1);
        u7 = cmul(w, buf[IX(base + 7*M)]);
    } else {
        u1 = buf[IX(base + M)];
        u2 = buf[IX(base + 2*M)];
        u3 = buf[IX(base + 3*M)];
        u4 = buf[IX(base + 4*M)];
        u5 = buf[IX(base + 5*M)];
        u6 = buf[IX(base + 6*M)];
        u7 = buf[IX(base + 7*M)];
    }
    float2 a0 = cadd(u0,u4), a1 = csub(u0,u4), a2 = cadd(u2,u6), a3 = csub(u2,u6);
    float2 E0 = cadd(a0,a2), E1 = addi(a1,a3), E2 = csub(a0,a2), E3 = subi(a1,a3);
    float2 c0 = cadd(u1,u5), c1 = csub(u1,u5), c2 = cadd(u3,u7), c3 = csub(u3,u7);
    float2 O0 = cadd(c0,c2), O1 = addi(c1,c3), O2 = csub(c0,c2), O3 = subi(c1,c3);
    float2 R1 = make_float2(s2*(O1.x - O1.y),  s2*(O1.x + O1.y));
    float2 R2 = make_float2(-O2.y, O2.x);
    float2 R3 = make_float2(-s2*(O3.x + O3.y), s2*(O3.x - O3.y));
    buf[IX(base)]       = cadd(E0,O0);
    buf[IX(base + 4*M)] = csub(E0,O0);
    buf[IX(base + M)]   = cadd(E1,R1);
    buf[IX(base + 5*M)] = csub(E1,R1);
    buf[IX(base + 2*M)] = cadd(E2,R2);
    buf[IX(base + 6*M)] = csub(E2,R2);
    buf[IX(base + 3*M)] = cadd(E3,R3);
    buf[IX(base + 7*M)] = csub(E3,R3);
}

// ---------------- K7: in-place FFT + mod + iFFT, fp16 xt ----------------
__global__ __launch_bounds__(512, 6) void k_fftmod(ushort_t* __restrict__ xt,
                                                   const float2* __restrict__ eff) {
    __shared__ float2 buf[4352];                // 4096 skewed
    __shared__ float2 tw[544];                  // W_4096^e, e<512, skewed
    int t = threadIdx.x;
    int sig0 = blockIdx.x * 2;                  // 2048 blocks
    int b = sig0 >> 10;
    int h = (sig0 & 1023) >> 6;
    const float2* ef = eff + ((size_t)b * H_ + h) * FB_;
    ushort_t* xs = xt + (size_t)sig0 * 4096;

    {
        float sv, cv;
        __sincosf(-(float)M_PI * (float)t * (1.0f / 2048.0f), &sv, &cv);
        tw[IX(t)] = make_float2(cv, sv);
    }
    {
        const uint4* pa = (const uint4*)xs;
        const uint4* pb = pa + 512;
        uint4 ua = pa[t], ub = pb[t];
        int n = t << 3;
        buf[IX(n+0)] = make_float2(lo_f(ua.x), lo_f(ub.x));
        buf[IX(n+1)] = make_float2(hi_f(ua.x), hi_f(ub.x));
        buf[IX(n+2)] = make_float2(lo_f(ua.y), lo_f(ub.y));
        buf[IX(n+3)] = make_float2(hi_f(ua.y), hi_f(ub.y));
        buf[IX(n+4)] = make_float2(lo_f(ua.z), lo_f(ub.z));
        buf[IX(n+5)] = make_float2(hi_f(ua.z), hi_f(ub.z));
        buf[IX(n+6)] = make_float2(lo_f(ua.w), lo_f(ub.w));
        buf[IX(n+7)] = make_float2(hi_f(ua.w), hi_f(ub.w));
    }
    __syncthreads();

    dif_stage<512, 0, true >(buf, tw, t); __syncthreads();
    dif_stage<64,  3, true >(buf, tw, t); __syncthreads();
    dif_stage<8,   6, true >(buf, tw, t); __syncthreads();
    dif_stage<1,   0, false>(buf, tw, t); __syncthreads();

    if (t == 0) {                                // k = 0 at p = 0
        float2 Z = buf[IX(0)];
        float2 e0 = ef[0];
        float Av = Z.x * e0.x + e0.y;
        float Bv = Z.y * e0.x + e0.y;
        float ma = fabsf(Av); Av *= gelu_t(ma) / (ma + 1e-6f);
        float mb = fabsf(Bv); Bv *= gelu_t(mb) / (mb + 1e-6f);
        buf[IX(0)] = make_float2(Av, Bv);
    }
    #pragma unroll
    for (int ii = 0; ii < 4; ii++) {
        int k = 1 + t + (ii << 9);               // 1..2048
        if (k == 2048) {                         // Nyquist at p = rev(2048) = 4
            float2 Z = buf[IX(4)];
            float2 eN = ef[2048];
            float Av = Z.x * eN.x + eN.y;
            float Bv = Z.y * eN.x + eN.y;
            float ma = fabsf(Av); Av *= gelu_t(ma) / (ma + 1e-6f);
            float mb = fabsf(Bv); Bv *= gelu_t(mb) / (mb + 1e-6f);
            buf[IX(4)] = make_float2(Av, Bv);
        } else {
            int pk = rev12(k);
            int pq = rev12(4096 - k);
            float2 Zk = buf[IX(pk)], Zq = buf[IX(pq)];
            float2 A  = make_float2(0.5f*(Zk.x + Zq.x), 0.5f*(Zk.y - Zq.y));
            float2 Bc = make_float2(0.5f*(Zk.y + Zq.y), 0.5f*(Zq.x - Zk.x));
            float2 e = ef[k];
            float2 Ap = make_float2(A.x * e.x + e.y,  A.y * e.x);
            float2 Bp = make_float2(Bc.x * e.x + e.y, Bc.y * e.x);
            Ap = cact(Ap); Bp = cact(Bp);
            buf[IX(pk)] = make_float2(Ap.x - Bp.y, Ap.y + Bp.x);
            buf[IX(pq)] = make_float2(Ap.x + Bp.y, Bp.x - Ap.y);
        }
    }
    __syncthreads();

    dit_stage<1,   0, false>(buf, tw, t); __syncthreads();
    dit_stage<8,   6, true >(buf, tw, t); __syncthreads();
    dit_stage<64,  3, true >(buf, tw, t); __syncthreads();
    dit_stage<512, 0, true >(buf, tw, t); __syncthreads();

    {
        const float sc = 1.0f / 4096.0f;
        int n = t << 3;
        float2 z0 = buf[IX(n+0)], z1 = buf[IX(n+1)], z2 = buf[IX(n+2)], z3 = buf[IX(n+3)];
        float2 z4 = buf[IX(n+4)], z5 = buf[IX(n+5)], z6 = buf[IX(n+6)], z7 = buf[IX(n+7)];
        uint4 oa, ob;
        oa.x = pk2(z0.x*sc, z1.x*sc); oa.y = pk2(z2.x*sc, z3.x*sc);
        oa.z = pk2(z4.x*sc, z5.x*sc); oa.w = pk2(z6.x*sc, z7.x*sc);
        ob.x = pk2(z0.y*sc, z1.y*sc); ob.y = pk2(z2.y*sc, z3.y*sc);
        ob.z = pk2(z4.y*sc, z5.y*sc); ob.w = pk2(z6.y*sc, z7.y*sc);
        ((uint4*)xs)[t] = oa;
        ((uint4*)xs)[t + 512] = ob;
    }
}

// ---------------- K8: transpose back to (B,N,D), fp16 -> fp32 ----------------
__global__ __launch_bounds__(256) void k_transout(const ushort_t* __restrict__ xt,
                                                  float* __restrict__ out) {
    __shared__ float tile[64 * 65];
    int bid = blockIdx.x;
    int b = bid >> 10;
    int rem = bid & 1023;
    int nt = rem >> 4;
    int dt = rem & 15;
    int n0 = nt << 6;
    int tx = threadIdx.x & 63, ty = threadIdx.x >> 6;
    const ushort_t* xtb = xt + ((size_t)((b * H_ + dt) * HD_)) * (size_t)N_ + n0;
    for (int r = 0; r < 16; r++) {
        int dloc = ty + 4 * r;
        tile[dloc * 65 + tx] = h2f(xtb[(size_t)dloc * N_ + tx]);
    }
    __syncthreads();
    float* ob = out + ((size_t)b * N_ + n0) * D_ + dt * HD_;
    for (int r = 0; r < 16; r++) {
        int nn = ty + 4 * r;
        ob[(size_t)nn * D_ + tx] = tile[tx * 65 + nn];
    }
}

extern "C" void kernel_launch(void* const* d_in, const int* in_sizes, int n_in,
                              void* d_out, int out_size, void* d_ws, size_t ws_size,
                              hipStream_t stream) {
    const float* x     = (const float*)d_in[0];
    const float* lnw   = (const float*)d_in[1];
    const float* lnb   = (const float*)d_in[2];
    const float* bfilt = (const float*)d_in[3];
    const float* bbias = (const float*)d_in[4];
    const float* w0    = (const float*)d_in[5];
    const float* b0    = (const float*)d_in[6];
    const float* w1    = (const float*)d_in[7];
    const float* b1    = (const float*)d_in[8];
    const float* w2    = (const float*)d_in[9];
    const float* b2    = (const float*)d_in[10];

    float* ws = (float*)d_ws;
    ushort_t* xt   = (ushort_t*)ws;                       // 16,777,216 fp16
    float*  cpart  = ws + 8388608;                        // 524,288
    float*  ctx    = ws + 8912896;                        // 4096
    float*  pA     = ws + 8916992;                        // 65,536 (16 slices x 4 x 1024)
    float*  pB     = ws + 8982528;                        // 65,536
    float*  p3     = ws + 9048064;                        // 2,098,176
    float2* eff    = (float2*)(ws + 11146240);            // 131,136 float2
    float*  out    = (float*)d_out;

    k_normT     <<<512,  256, 0, stream>>>(x, lnw, lnb, xt, cpart);
    k_ctx       <<<16,   256, 0, stream>>>(cpart, ctx);
    k_mlp_part  <<<dim3(16, 16), 256, 0, stream>>>(ctx, w0, pA);
    k_mlp_part2 <<<dim3(16, 16), 256, 0, stream>>>(pA, b0, w1, pB);
    k_adapt_part<<<dim3(65, 8), 256, 0, stream>>>(pB, b1, w2, p3);
    k_eff       <<<129,  256, 0, stream>>>(p3, b2, bfilt, bbias, eff);
    k_fftmod    <<<2048, 512, 0, stream>>>(xt, eff);
    k_transout  <<<4096, 256, 0, stream>>>(xt, out);
}